// Round 1
// 227.639 us; speedup vs baseline: 1.0446x; 1.0446x over previous
//
#include <hip/hip_runtime.h>

// BEiT self-attention: B=64, S=197, D=768, H=12, HD=64
// Pipeline:
//   1. k_prep      : fused grid-stride prep — hidden fp32->bf16 (pad rows zero),
//                    W combine fp32->bf16 [2304][768], bias -> MFMA-C-frag layout
//   2. k_gemm_qkv  : 256x256 / BK=64 / 8-wave, 4-phase-per-K-tile schedule with
//                    counted vmcnt(6) (loads stay in flight across barriers),
//                    full 3-bit XOR LDS swizzle (8-dword/bank minimum),
//                    s_setprio around MFMA clusters, bijective XCD remap.
//                    A padded to 12800 rows; C stores masked at 12672.
//   3. k_attn_mfma : transposed attention S^T=K*Q^T, O^T=V^T*P^T; K a-frags + V^T in LDS;
//                    P via quad-shfl transform; no barriers in main loop

#define S_LEN 197
#define HEADS 12
#define HDIM 64
#define DMODEL 768
#define BATCH 64
#define MROWS (BATCH * S_LEN) /* 12608 */
#define MPAD_C 12672          /* Cb rows (unchanged vs previous version) */
#define MPAD_A 12800          /* hbf rows: 50 * 256 (A-side zero padding) */
#define NCOLS (3 * DMODEL) /* 2304 */
#define KDIM DMODEL
#define NQT 13 /* ceil(197/16) */
#define NWG 450 /* 50 m-tiles * 9 n-tiles of 256 */

typedef __attribute__((ext_vector_type(8))) short short8;
typedef __attribute__((ext_vector_type(4))) float floatx4;

#define GLD16(gp, lp)                                                                  \
  __builtin_amdgcn_global_load_lds(                                                    \
      (const __attribute__((address_space(1))) unsigned int*)(gp),                     \
      (__attribute__((address_space(3))) unsigned int*)(lp), 16, 0, 0)

__device__ __forceinline__ ushort f2bf(float f) {
  union { float f; unsigned int i; } x;
  x.f = f;
  unsigned int r = x.i + 0x7fffu + ((x.i >> 16) & 1u); // RNE
  return (ushort)(r >> 16);
}

// fused prep: one launch, grid-stride over three independent sections
__global__ __launch_bounds__(256) void k_prep(
    const float* __restrict__ hs, const float* __restrict__ wq,
    const float* __restrict__ wk, const float* __restrict__ wv,
    const float* __restrict__ bt, const int* __restrict__ ridx,
    ushort* __restrict__ hbf, ushort* __restrict__ wbf, float* __restrict__ biasF) {
  int gid = blockIdx.x * 256 + threadIdx.x;
  int gsz = gridDim.x * 256;
  // hidden -> bf16, rows >= MROWS zeroed (up to MPAD_A)
  for (int i = gid; i < MPAD_A * KDIM / 8; i += gsz) {
    int base = i * 8;
    int row = base / KDIM;
    ushort o[8];
    if (row < MROWS) {
      const float* s = hs + (size_t)base;
#pragma unroll
      for (int e = 0; e < 8; ++e) o[e] = f2bf(s[e]);
    } else {
#pragma unroll
      for (int e = 0; e < 8; ++e) o[e] = 0;
    }
    *(uint4*)&hbf[base] = *(const uint4*)o;
  }
  // weights -> combined bf16 [2304][768]
  for (int i = gid; i < NCOLS * KDIM / 8; i += gsz) {
    int base = i * 8;
    int row = base / KDIM;
    int col = base - row * KDIM;
    const float* src = (row < DMODEL) ? &wq[(size_t)row * KDIM]
                       : (row < 2 * DMODEL) ? &wk[(size_t)(row - DMODEL) * KDIM]
                                            : &wv[(size_t)(row - 2 * DMODEL) * KDIM];
    ushort o[8];
#pragma unroll
    for (int e = 0; e < 8; ++e) o[e] = f2bf(src[col + e]);
    *(uint4*)&wbf[base] = *(const uint4*)o;
  }
  // biasF[h][qt][t][lane][r]: C-frag of S^T tile (row=key=quad*4+r, col=q=l16); mask baked
  for (int idx = gid; idx < HEADS * NQT * NQT * 64; idx += gsz) {
    int lane = idx & 63;
    int rest = idx >> 6;
    int t = rest % NQT;
    int rest2 = rest / NQT;
    int qt = rest2 % NQT;
    int h = rest2 / NQT;
    int l16 = lane & 15, quad = lane >> 4;
    int q = qt * 16 + l16;
    floatx4 v;
#pragma unroll
    for (int r = 0; r < 4; ++r) {
      int key = t * 16 + quad * 4 + r;
      float x = -1e30f;
      if (q < S_LEN && key < S_LEN) x = bt[ridx[q * S_LEN + key] * HEADS + h];
      v[r] = x;
    }
    *(floatx4*)&biasF[(size_t)idx * 4] = v;
  }
}

// 256x256 tile, BK=64, 12 K-tiles, double-buffered 128KB LDS.
// 8 waves (2 row x 4 col), per-wave output 128x64, acc[8][4] floatx4.
// LDS swizzle: slot (r,c) holds global chunk c^(r&7) -> 8-dword/bank minimum on
// both the lane-linear global_load_lds writes and the ds_read_b128 frag reads.
// Phase order per K-tile: (i0,j0),(i0,j1),(i1,j1),(i1,j0); ds_reads 12/4/8/0.
// Prefetch tile t+2 into the CURRENT buffer, quarter-slabs issued one phase after
// their region's last reader; vmcnt(6) once per K-tile (never 0 until tail).
__global__ __launch_bounds__(512) void k_gemm_qkv(
    const ushort* __restrict__ A, const ushort* __restrict__ W,
    const float* __restrict__ bq, const float* __restrict__ bv,
    ushort* __restrict__ Cb) {
  __shared__ __align__(16) ushort SH[65536]; // 128KB: A0,A1,B0,B1 each [256][64]
  int tid = threadIdx.x;
  int wave = tid >> 6, lane = tid & 63;
  int quad = lane >> 4, l16 = lane & 15;
  int wr = wave >> 2, wc = wave & 3;

  // bijective XCD remap for 450 blocks (450 = 8*56 + 2, m204 formula);
  // consecutive wgid within an XCD run row-major -> W-panel reuse in its L2.
  int orig = blockIdx.x;
  int x = orig & 7, pp = orig >> 3;
  int wgid = (x < 2 ? x * 57 : 114 + (x - 2) * 56) + pp;
  int m_t = wgid / 9, n_t = wgid - m_t * 9;
  int m0 = m_t * 256, n0 = n_t * 256;

  // staging geometry: thread -> (row rl, chunk-slot ccol); slot holds global chunk gchunk
  int rl = tid >> 3, ccol = tid & 7;
  int gchunk = ccol ^ (rl & 7);
  const ushort* srcA = A + (size_t)(m0 + rl) * KDIM + gchunk * 8;
  const ushort* srcB = W + (size_t)(n0 + rl) * KDIM + gchunk * 8;
  int dst0 = tid * 8; // lane-linear 16B dest (wave-uniform base + lane*16)

#define ISSA(u, q) GLD16(srcA + (size_t)(q) * 64 * KDIM + (u) * 64, \
                         &SH[(((u) & 1) * 16384) + (q) * 4096 + dst0])
#define ISSB(u, q) GLD16(srcB + (size_t)(q) * 64 * KDIM + (u) * 64, \
                         &SH[32768 + (((u) & 1) * 16384) + (q) * 4096 + dst0])

  // frag read offsets: row = (band + l16), k-chunk g=ks*4+quad at slot g^(l16&7)
  int s7 = l16 & 7;
  int aoff[2], boff[2];
#pragma unroll
  for (int ks = 0; ks < 2; ++ks) {
    int slot = ((ks * 4 + quad) ^ s7) << 3;
    aoff[ks] = (wr * 128 + l16) * 64 + slot;
    boff[ks] = (wc * 64 + l16) * 64 + slot;
  }

  floatx4 acc[8][4];
  floatx4 z = {0.f, 0.f, 0.f, 0.f};
#pragma unroll
  for (int i = 0; i < 8; ++i)
#pragma unroll
    for (int j = 0; j < 4; ++j) acc[i][j] = z;

  // prologue: tile0 full (8 loads), tile1 minus Aq1,Aq3 (6 loads; those are the
  // steady-state phase-1 carry). vmcnt(6) -> tile0 landed, tile1's 6 in flight.
  ISSA(0, 0); ISSA(0, 1); ISSA(0, 2); ISSA(0, 3);
  ISSB(0, 0); ISSB(0, 1); ISSB(0, 2); ISSB(0, 3);
  ISSA(1, 0); ISSA(1, 2);
  ISSB(1, 0); ISSB(1, 1); ISSB(1, 2); ISSB(1, 3);
  asm volatile("s_waitcnt vmcnt(6)" ::: "memory");
  __builtin_amdgcn_s_barrier();
  asm volatile("" ::: "memory");

#pragma unroll 2
  for (int t = 0; t < 12; ++t) {
    const ushort* Ab = &SH[(t & 1) * 16384];
    const ushort* Bb = &SH[32768 + (t & 1) * 16384];
    short8 a0[2][4], a1[2][4], b0[2][2], b1[2][2];
    // ---- phase 1: (i0,j0); reads A-i0 (8) + B-j0 (4); issue tile t+1 Aq1,Aq3
#pragma unroll
    for (int ks = 0; ks < 2; ++ks) {
#pragma unroll
      for (int i = 0; i < 4; ++i) a0[ks][i] = *(const short8*)&Ab[aoff[ks] + i * 1024];
#pragma unroll
      for (int j = 0; j < 2; ++j) b0[ks][j] = *(const short8*)&Bb[boff[ks] + j * 1024];
    }
    if (t <= 10) { ISSA(t + 1, 1); ISSA(t + 1, 3); }
    asm volatile("s_waitcnt lgkmcnt(8)" ::: "memory");
    __builtin_amdgcn_s_barrier();
    asm volatile("s_waitcnt lgkmcnt(0)" ::: "memory");
    __builtin_amdgcn_s_setprio(1);
#pragma unroll
    for (int i = 0; i < 4; ++i)
#pragma unroll
      for (int j = 0; j < 2; ++j) {
        acc[i][j] = __builtin_amdgcn_mfma_f32_16x16x32_bf16(a0[0][i], b0[0][j], acc[i][j], 0, 0, 0);
        acc[i][j] = __builtin_amdgcn_mfma_f32_16x16x32_bf16(a0[1][i], b0[1][j], acc[i][j], 0, 0, 0);
      }
    __builtin_amdgcn_s_setprio(0);
    __builtin_amdgcn_s_barrier();
    // ---- phase 2: (i0,j1); reads B-j1 (4); issue tile t+2 Aq0,Aq2 (A-i0 freed ph1)
#pragma unroll
    for (int ks = 0; ks < 2; ++ks)
#pragma unroll
      for (int j = 0; j < 2; ++j) b1[ks][j] = *(const short8*)&Bb[boff[ks] + (2 + j) * 1024];
    if (t <= 9) { ISSA(t + 2, 0); ISSA(t + 2, 2); }
    __builtin_amdgcn_s_barrier();
    asm volatile("s_waitcnt lgkmcnt(0)" ::: "memory");
    __builtin_amdgcn_s_setprio(1);
#pragma unroll
    for (int i = 0; i < 4; ++i)
#pragma unroll
      for (int j = 0; j < 2; ++j) {
        acc[i][2 + j] = __builtin_amdgcn_mfma_f32_16x16x32_bf16(a0[0][i], b1[0][j], acc[i][2 + j], 0, 0, 0);
        acc[i][2 + j] = __builtin_amdgcn_mfma_f32_16x16x32_bf16(a0[1][i], b1[1][j], acc[i][2 + j], 0, 0, 0);
      }
    __builtin_amdgcn_s_setprio(0);
    __builtin_amdgcn_s_barrier();
    // ---- phase 3: (i1,j1); reads A-i1 (8); issue tile t+2 Bq0,Bq1 (B freed ph2)
#pragma unroll
    for (int ks = 0; ks < 2; ++ks)
#pragma unroll
      for (int i = 0; i < 4; ++i) a1[ks][i] = *(const short8*)&Ab[aoff[ks] + (4 + i) * 1024];
    if (t <= 9) { ISSB(t + 2, 0); ISSB(t + 2, 1); }
    __builtin_amdgcn_s_barrier();
    asm volatile("s_waitcnt lgkmcnt(0)" ::: "memory");
    __builtin_amdgcn_s_setprio(1);
#pragma unroll
    for (int i = 0; i < 4; ++i)
#pragma unroll
      for (int j = 0; j < 2; ++j) {
        acc[4 + i][2 + j] = __builtin_amdgcn_mfma_f32_16x16x32_bf16(a1[0][i], b1[0][j], acc[4 + i][2 + j], 0, 0, 0);
        acc[4 + i][2 + j] = __builtin_amdgcn_mfma_f32_16x16x32_bf16(a1[1][i], b1[1][j], acc[4 + i][2 + j], 0, 0, 0);
      }
    __builtin_amdgcn_s_setprio(0);
    __builtin_amdgcn_s_barrier();
    // ---- phase 4: (i1,j0); no reads; issue tile t+2 Bq2,Bq3; end-of-tile vmcnt
    if (t <= 9) { ISSB(t + 2, 2); ISSB(t + 2, 3); }
    __builtin_amdgcn_s_barrier();
    __builtin_amdgcn_s_setprio(1);
#pragma unroll
    for (int i = 0; i < 4; ++i)
#pragma unroll
      for (int j = 0; j < 2; ++j) {
        acc[4 + i][j] = __builtin_amdgcn_mfma_f32_16x16x32_bf16(a1[0][i], b0[0][j], acc[4 + i][j], 0, 0, 0);
        acc[4 + i][j] = __builtin_amdgcn_mfma_f32_16x16x32_bf16(a1[1][i], b0[1][j], acc[4 + i][j], 0, 0, 0);
      }
    __builtin_amdgcn_s_setprio(0);
    if (t <= 9) asm volatile("s_waitcnt vmcnt(6)" ::: "memory");
    else        asm volatile("s_waitcnt vmcnt(0)" ::: "memory");
    __builtin_amdgcn_s_barrier();
    asm volatile("" ::: "memory");
  }
#undef ISSA
#undef ISSB

  // epilogue: two 128-row passes through SH [128][256] (swizzled bf16), then
  // full-line dwordx4 stores; bias + Q-scale fused; rows >= MPAD_C masked.
#pragma unroll
  for (int P = 0; P < 2; ++P) {
    __syncthreads();
    if (wr == P) {
#pragma unroll
      for (int j = 0; j < 4; ++j) {
        int cn = wc * 64 + j * 16 + l16;
        int col = n0 + cn;
        float bias = (col < DMODEL) ? bq[col] : ((col >= 2 * DMODEL) ? bv[col - 2 * DMODEL] : 0.f);
        float scl = (col < DMODEL) ? 0.125f : 1.0f;
#pragma unroll
        for (int i = 0; i < 8; ++i)
#pragma unroll
          for (int r = 0; r < 4; ++r) {
            int lr = i * 16 + quad * 4 + r;
            int ch = (cn >> 3) ^ (lr & 7);
            SH[lr * 256 + (ch << 3) + (cn & 7)] = f2bf((acc[i][j][r] + bias) * scl);
          }
      }
    }
    __syncthreads();
#pragma unroll
    for (int k = 0; k < 8; ++k) {
      int c0 = k * 512 + tid;
      int lr = c0 >> 5, ch = c0 & 31;
      int grow = m0 + P * 128 + lr;
      if (grow < MPAD_C) {
        *(uint4*)&Cb[(size_t)grow * NCOLS + n0 + ch * 8] =
            *(const uint4*)&SH[lr * 256 + ((ch ^ (lr & 7)) << 3)];
      }
    }
  }
}

// Transposed MFMA attention. One block per (b,h), 4 independent waves (qt = wave+4k).
// K a-frags staged once into LDS (lane-linear, conflict-free); V^T in swizzled LDS.
// S^T = K*Q^T (C-layout row=key, col=q). Softmax per column (2 shfls). P -> PV B-frag
// via quad-transpose shfl. O^T = V^T * P^T -> per-lane float4 stores.
__global__ __launch_bounds__(256) void k_attn_mfma(
    const ushort* __restrict__ Cb0, const float* __restrict__ biasF,
    float* __restrict__ out) {
  __shared__ __align__(16) ushort Vt[HDIM * 256];     // 32768 B, [d][key] swizzled
  __shared__ __align__(16) ushort Ka[NQT * 2 * 512];  // 26624 B, [t][half][lane][8]
  int bh = blockIdx.x;
  int b = bh / HEADS, h = bh - b * HEADS;
  int tid = threadIdx.x;
  int wave = tid >> 6, lane = tid & 63;
  int quad = lane >> 4, l16 = lane & 15;
  const ushort* Cb = Cb0 + (size_t)b * S_LEN * NCOLS;
  const int qoff = h * HDIM, koff = DMODEL + h * HDIM, voff = 2 * DMODEL + h * HDIM;

  { // zero Vt (key cols 197..255 must be 0.0)
    uint4 z4 = {0u, 0u, 0u, 0u};
    for (int i = tid; i < HDIM * 256 / 8; i += 256) ((uint4*)Vt)[i] = z4;
  }
  __syncthreads();
  for (int idx = tid; idx < S_LEN * 32; idx += 256) { // V -> V^T (swizzled scatter)
    int key = idx >> 5, dp = (idx & 31) * 2;
    unsigned int v = *(const unsigned int*)&Cb[(size_t)key * NCOLS + voff + dp];
    int ch = key >> 3, co = key & 7;
    Vt[dp * 256 + ((ch ^ (dp & 7)) << 3) + co] = (ushort)(v & 0xffffu);
    Vt[(dp + 1) * 256 + ((ch ^ ((dp + 1) & 7)) << 3) + co] = (ushort)(v >> 16);
  }
  // stage K a-frags: rows up to 207 read neighbor-batch data (finite; masked by bias)
  for (int th = wave; th < NQT * 2; th += 4) {
    int t = th >> 1, half = th & 1;
    short8 kf = *(const short8*)&Cb[(size_t)(t * 16 + l16) * NCOLS + koff + half * 32 + quad * 8];
    *(short8*)&Ka[th * 512 + lane * 8] = kf;
  }
  __syncthreads(); // last barrier; waves independent below

  for (int qt = wave; qt < NQT; qt += 4) {
    int q0 = qt * 16;
    int q = q0 + l16;
    short8 qb0 = *(const short8*)&Cb[(size_t)q * NCOLS + qoff + quad * 8];
    short8 qb1 = *(const short8*)&Cb[(size_t)q * NCOLS + qoff + 32 + quad * 8];
    const float* bF = biasF + ((size_t)((h * NQT + qt) * NQT) * 64 + lane) * 4;

    floatx4 sacc[NQT];
#pragma unroll
    for (int t = 0; t < NQT; ++t) {
      floatx4 cin = *(const floatx4*)&bF[t * 256]; // bias as MFMA C-init (mask baked in)
      short8 ka0 = *(const short8*)&Ka[(t * 2 + 0) * 512 + lane * 8];
      short8 ka1 = *(const short8*)&Ka[(t * 2 + 1) * 512 + lane * 8];
      floatx4 s1 = __builtin_amdgcn_mfma_f32_16x16x32_bf16(ka0, qb0, cin, 0, 0, 0);
      sacc[t] = __builtin_amdgcn_mfma_f32_16x16x32_bf16(ka1, qb1, s1, 0, 0, 0);
    }

    // softmax over keys (spread across quads+regs+tiles at fixed col q)
    float mx = -3e38f;
#pragma unroll
    for (int t = 0; t < NQT; ++t)
#pragma unroll
      for (int r = 0; r < 4; ++r) mx = fmaxf(mx, sacc[t][r]);
    mx = fmaxf(mx, __shfl_xor(mx, 16));
    mx = fmaxf(mx, __shfl_xor(mx, 32));
    float sum = 0.f;
    unsigned int pbf[NQT][2]; // packed bf16 pairs (rows 2r,2r+1), unnormalized
#pragma unroll
    for (int t = 0; t < NQT; ++t) {
      float e0 = __expf(sacc[t][0] - mx), e1 = __expf(sacc[t][1] - mx);
      float e2 = __expf(sacc[t][2] - mx), e3 = __expf(sacc[t][3] - mx);
      sum += (e0 + e1) + (e2 + e3);
      union { float f; unsigned int u; } a, bb, c, d;
      a.f = e0; bb.f = e1; c.f = e2; d.f = e3;
      pbf[t][0] = ((a.u + 0x8000u) >> 16) | ((bb.u + 0x8000u) & 0xffff0000u);
      pbf[t][1] = ((c.u + 0x8000u) >> 16) | ((d.u + 0x8000u) & 0xffff0000u);
    }
    sum += __shfl_xor(sum, 16);
    sum += __shfl_xor(sum, 32);
    float inv = 1.f / sum;

    // PV: O^T[d][q]; B-frag(P) lane(quad,l16) needs keys kk*32+quad*8+j of col q=l16
    floatx4 oacc[4];
    floatx4 zz = {0.f, 0.f, 0.f, 0.f};
#pragma unroll
    for (int dt = 0; dt < 4; ++dt) oacc[dt] = zz;
    int sel0 = ((quad & 1) * 2) * 16 + l16;
    int sel1 = sel0 + 16;
#pragma unroll
    for (int kk = 0; kk < 7; ++kk) {
      unsigned int u0 = 0, u1 = 0, u2 = 0, u3 = 0;
#pragma unroll
      for (int half = 0; half < 2; ++half) {
        int t = 2 * kk + half;
        if (t < NQT) {
          unsigned int v0 = __shfl((int)pbf[t][0], sel0);
          unsigned int v1 = __shfl((int)pbf[t][1], sel0);
          unsigned int v2 = __shfl((int)pbf[t][0], sel1);
          unsigned int v3 = __shfl((int)pbf[t][1], sel1);
          if ((quad >> 1) == half) { u0 = v0; u1 = v1; u2 = v2; u3 = v3; }
        }
      }
      union { uint4 u; short8 s; } pf;
      pf.u.x = u0; pf.u.y = u1; pf.u.z = u2; pf.u.w = u3;
#pragma unroll
      for (int dt = 0; dt < 4; ++dt) {
        int d = dt * 16 + l16;
        short8 vf = *(const short8*)&Vt[d * 256 + (((kk * 4 + quad) ^ (d & 7)) << 3)];
        oacc[dt] = __builtin_amdgcn_mfma_f32_16x16x32_bf16(vf, pf.s, oacc[dt], 0, 0, 0);
      }
    }

    // O^T C-layout: row=d=dt*16+quad*4+r, col=q=l16 -> per-lane float4 of consecutive d
    if (q < S_LEN) {
      float* og = out + ((size_t)b * S_LEN + q) * DMODEL + h * HDIM + quad * 4;
#pragma unroll
      for (int dt = 0; dt < 4; ++dt) {
        floatx4 o = oacc[dt];
        float4 st = make_float4(o[0] * inv, o[1] * inv, o[2] * inv, o[3] * inv);
        *(float4*)&og[dt * 16] = st;
      }
    }
  }
}

extern "C" void kernel_launch(void* const* d_in, const int* in_sizes, int n_in,
                              void* d_out, int out_size, void* d_ws, size_t ws_size,
                              hipStream_t stream) {
  const float* hs = (const float*)d_in[0];
  const float* wq = (const float*)d_in[1];
  const float* bq = (const float*)d_in[2];
  const float* wk = (const float*)d_in[3];
  const float* wv = (const float*)d_in[4];
  const float* bv = (const float*)d_in[5];
  const float* bt = (const float*)d_in[6];
  const int* ridx = (const int*)d_in[7];
  float* out = (float*)d_out;

  // workspace (~83.7 MB)
  ushort* hbf = (ushort*)d_ws;                // [12800][768] bf16
  ushort* wbf = hbf + (size_t)MPAD_A * KDIM;  // [2304][768] bf16
  ushort* Cb = wbf + (size_t)NCOLS * KDIM;    // [12672][2304] bf16 (QKV combined)
  float* biasF = (float*)(Cb + (size_t)MPAD_C * NCOLS); // [12][13][13][64][4] fp32

  k_prep<<<2048, 256, 0, stream>>>(hs, wq, wk, wv, bt, ridx, hbf, wbf, biasF);
  k_gemm_qkv<<<NWG, 512, 0, stream>>>(hbf, wbf, bq, bv, Cb);
  k_attn_mfma<<<BATCH * HEADS, 256, 0, stream>>>(Cb, biasF, out);
}